// Round 1
// baseline (345.639 us; speedup 1.0000x reference)
//
#include <hip/hip_runtime.h>
#include <hip/hip_bf16.h>

// RoleSensitiveEmbedding: out[t,:] = W_{role[t]} @ emb[ids[t],:]
// R4: eliminate the separate gather pass + X buffer. k_pre partitions tokens
// (two-sided atomic packing) and records tokid[row] = ids[perm[row]]; k_gemm
// stages its A-tile DIRECTLY from emb (fp32) via per-lane-gathered
// global_load_lds into a 32KB fp32 LDS tile (32B-granular XOR swizzle on
// both source-address and ds_read sides), converting f32->bf16 at
// fragment-read time with v_cvt_pk_bf16_f32. 1 memset + 2 kernels.

#define M_TOK   16384
#define DIM     1024
#define MT      128                 // gemm m-tile rows
#define NTIL    130                 // ceil(n0/128)+ceil(n1/128) <= 130 always
#define XROWS   (NTIL * MT)         // 16640
#define BK      64
#define PBLK    64                  // partition blocks (64*256 = 16384 tokens)
#define WBLKS   2048                // 2*1024*1024 floats / (256 thr * 4)

typedef __attribute__((ext_vector_type(8))) short short8;
typedef __attribute__((ext_vector_type(4))) float f32x4;
typedef __attribute__((ext_vector_type(4))) unsigned int uint32x4;

// ---- workspace layout (bytes) ----
#define OFF_TOK  256                // tokid[XROWS] : 66560 B
#define OFF_PERM 66816              // perm[XROWS]  : 66560 B
#define OFF_WB   133376             // Wb: 2*1024*1024 bf16 = 4 MB
// total ~4.33 MB ; memset covers [0, OFF_PERM) = cnt + tokid

static __device__ __forceinline__ unsigned short f2bf(float f) {
    unsigned int u = __float_as_uint(f);
    u += 0x7fffu + ((u >> 16) & 1u);   // round-to-nearest-even
    return (unsigned short)(u >> 16);
}

static __device__ __forceinline__ unsigned int pk2(float a, float b) {
    __hip_bfloat162 h = __float22bfloat162_rn(make_float2(a, b));
    union { __hip_bfloat162 h; unsigned int u; } c;
    c.h = h;
    return c.u;
}

// blocks [0,PBLK): role partition via two-sided atomic packing; each thread
// also records tokid[row] = ids[t] so the GEMM needs no second indirection.
// blocks [PBLK, PBLK+WBLKS): convert W0|W1 fp32 -> bf16 Wb
__global__ void k_pre(const int* __restrict__ role, const int* __restrict__ ids,
                      int* perm, int* tokid, int* cnt,
                      const float* __restrict__ W0, const float* __restrict__ W1,
                      unsigned short* __restrict__ Wb) {
    int b = blockIdx.x;
    if (b < PBLK) {
        int t = b * 256 + threadIdx.x;           // 0..16383
        int row;
        if (role[t] == 1) { int s = atomicAdd(&cnt[1], 1); row = XROWS - 1 - s; }
        else              { int s = atomicAdd(&cnt[0], 1); row = s; }
        perm[row]  = t;
        tokid[row] = ids[t];
    } else {
        int idx = ((b - PBLK) * 256 + threadIdx.x) * 4;   // 0 .. 2*1048576-4
        const float* src = (idx < 1048576) ? (W0 + idx) : (W1 + (idx - 1048576));
        float4 f = *(const float4*)src;
        *(ushort4*)(Wb + idx) = make_ushort4(f2bf(f.x), f2bf(f.y), f2bf(f.z), f2bf(f.w));
    }
}

// 128x128 tile GEMM, C = A * B^T.
//   A = emb rows gathered on the fly (fp32 in LDS, cvt->bf16 at frag read)
//   B^T = Wb rows (bf16 in LDS, unchanged path)
// A-tile LDS layout: 128 rows x 8 slices of 32B (8 f32); slice position
// p = m ^ (row&7) (involution applied on the global SOURCE address at staging
// and on the ds_read address — rule #21). Gap rows have tokid==0 -> emb row 0
// (the all-zero padding row), so no wild addresses and MFMA garbage is benign
// (epilogue bounds-guards the scatter).
__global__ __launch_bounds__(256, 3)
void k_gemm(const float* __restrict__ emb, const unsigned short* __restrict__ Wbu,
            const int* __restrict__ perm, const int* __restrict__ tokid,
            const int* __restrict__ cnt, float* __restrict__ out) {
    __shared__ float As[MT * BK];      // 32 KB fp32
    __shared__ short Bs[MT * BK];      // 16 KB bf16

    // XCD swizzle: all 8 n-tiles of an m-tile share one XCD's L2
    int f  = blockIdx.x;
    int mt = ((f >> 6) << 3) | (f & 7);
    int nt = (f >> 3) & 7;
    if (mt >= NTIL) return;

    int n0 = cnt[0], n1 = cnt[1];
    int T0 = (n0 + 127) >> 7, T1 = (n1 + 127) >> 7;
    int e, lo, hi;
    if (mt < T0)              { e = 0; lo = 0;            hi = n0;    }
    else if (mt >= NTIL - T1) { e = 1; lo = XROWS - n1;   hi = XROWS; }
    else return;                           // gap tile

    const short* Bg = (const short*)Wbu + (size_t)e * DIM * DIM + (size_t)nt * MT * DIM;

    int tid  = threadIdx.x;
    int lane = tid & 63;
    int w    = tid >> 6;         // wave 0..3
    int wm   = w & 1, wn = w >> 1;
    int quad = lane >> 4, lq = lane & 15;

    // Hoisted A staging source offsets (bytes from emb). Issue q covers LDS
    // 16B-slots s = (q*4+w)*64 + lane; row = s>>4 = 16q+4w+quad is fixed per
    // thread for the whole K-loop, so the tokid indirection hoists here.
    unsigned int aoff[8];
#pragma unroll
    for (int q = 0; q < 8; ++q) {
        int row = 16 * q + 4 * w + quad;
        int kf  = (((lq >> 1) ^ (row & 7)) << 3) | ((lq & 1) << 2);  // floats
        aoff[q] = (unsigned int)tokid[mt * MT + row] * (DIM * 4) + kf * 4;
    }
    // Hoisted B staging offsets (bytes from Bg), 16B-granular XOR swizzle
    unsigned int boff[4];
#pragma unroll
    for (int q = 0; q < 4; ++q) {
        int s   = (q * 4 + w) * 64 + lane;
        int row = s >> 3;
        int kc  = (s & 7) ^ (row & 7);
        boff[q] = (unsigned int)(row * DIM + kc * 8) * 2;
    }

    f32x4 acc[4][4] = {};

    for (int k0 = 0; k0 < DIM; k0 += BK) {
#pragma unroll
        for (int q = 0; q < 8; ++q) {
            int s = (q * 4 + w) * 64 + lane;     // lane-affine: HW uses base+lane*16
            __builtin_amdgcn_global_load_lds(
                (const __attribute__((address_space(1))) unsigned int*)((const char*)emb + aoff[q] + k0 * 4),
                (__attribute__((address_space(3))) unsigned int*)(&As[s * 4]),
                16, 0, 0);
        }
#pragma unroll
        for (int q = 0; q < 4; ++q) {
            int s = (q * 4 + w) * 64 + lane;
            __builtin_amdgcn_global_load_lds(
                (const __attribute__((address_space(1))) unsigned int*)((const char*)Bg + boff[q] + k0 * 2),
                (__attribute__((address_space(3))) unsigned int*)(&Bs[s * 8]),
                16, 0, 0);
        }
        __syncthreads();

#pragma unroll
        for (int s = 0; s < 2; ++s) {
            int s4q = s * 4 + quad;
            short8 bv[4];
#pragma unroll
            for (int j = 0; j < 4; ++j) {
                int rb = wn * 64 + j * 16 + lq;
                bv[j] = *(const short8*)&Bs[(rb * 8 + (s4q ^ (rb & 7))) * 8];
            }
#pragma unroll
            for (int i = 0; i < 4; ++i) {
                int ra = wm * 64 + i * 16 + lq;
                int p  = s4q ^ (ra & 7);
                const f32x4* ap = (const f32x4*)&As[ra * BK + p * 8];
                f32x4 fl = ap[0], fh = ap[1];
                union { uint32x4 u; short8 v; } av;
                av.u[0] = pk2(fl[0], fl[1]);
                av.u[1] = pk2(fl[2], fl[3]);
                av.u[2] = pk2(fh[0], fh[1]);
                av.u[3] = pk2(fh[2], fh[3]);
#pragma unroll
                for (int j = 0; j < 4; ++j)
                    acc[i][j] = __builtin_amdgcn_mfma_f32_16x16x32_bf16(
                        av.v, bv[j], acc[i][j], 0, 0, 0);
            }
        }
        __syncthreads();
    }

    // epilogue: C/D map m = quad*4+reg, n = lq; scatter rows to out[token,:]
    int colbase = nt * 128 + wn * 64 + lq;
#pragma unroll
    for (int i = 0; i < 4; ++i) {
#pragma unroll
        for (int r = 0; r < 4; ++r) {
            int mrow = mt * MT + wm * 64 + i * 16 + quad * 4 + r;
            if (mrow < lo || mrow >= hi) continue;   // gap row (bounds, not sentinel)
            int token = perm[mrow];
            float* o = out + (size_t)token * DIM + colbase;
#pragma unroll
            for (int j = 0; j < 4; ++j)
                o[j * 16] = acc[i][j][r];
        }
    }
}

extern "C" void kernel_launch(void* const* d_in, const int* in_sizes, int n_in,
                              void* d_out, int out_size, void* d_ws, size_t ws_size,
                              hipStream_t stream) {
    const int*   ids  = (const int*)d_in[0];
    const int*   role = (const int*)d_in[1];
    const float* emb  = (const float*)d_in[2];
    const float* W0   = (const float*)d_in[3];
    const float* W1   = (const float*)d_in[4];
    float*       out  = (float*)d_out;

    char* ws = (char*)d_ws;
    int* cnt   = (int*)ws;
    int* tokid = (int*)(ws + OFF_TOK);
    int* perm  = (int*)(ws + OFF_PERM);
    unsigned short* Wb = (unsigned short*)(ws + OFF_WB);

    // zero cnt + tokid (gap rows must point at emb row 0, the zero pad row)
    hipMemsetAsync(ws, 0x00, OFF_PERM, stream);
    k_pre <<<PBLK + WBLKS, 256, 0, stream>>>(role, ids, perm, tokid, cnt, W0, W1, Wb);
    k_gemm<<<1088,         256, 0, stream>>>(emb, Wb, perm, tokid, cnt, out);
}

// Round 2
// 332.026 us; speedup vs baseline: 1.0410x; 1.0410x over previous
//
#include <hip/hip_runtime.h>

// RoleSensitiveEmbedding: out[t,:] = W_{role[t]} @ emb[ids[t],:]
// Partition tokens by role (atomic two-sided packing) -> bf16 MFMA GEMM per
// region (half the FLOPs of reference's compute-both-and-select).
// R5: revert R4's fused fp32-A staging (regressed: 2x staging bytes + cvt on
// MFMA critical path + 8x emb re-fetch). Back to R3's proven 3-kernel plan
// (326us anchor), with ONE change: k_gather batches 8 rows/block (2080 blocks
// instead of 16640) so the perm->ids->emb dependent chains unroll into 8
// independent MLP streams and per-block dispatch overhead amortizes 8x.

#define M_TOK   16384
#define DIM     1024
#define MT      128                 // gemm m-tile rows
#define NTIL    130                 // ceil(n0/128)+ceil(n1/128) <= 130 always
#define XROWS   (NTIL * MT)         // 16640
#define BK      64
#define PBLK    64                  // perm blocks (64*256 = 16384 tokens)
#define WBLKS   2048                // 2*1024*1024 floats / (256 thr * 4)
#define GROWS   8                   // gather rows per block

typedef __attribute__((ext_vector_type(8))) short short8;
typedef __attribute__((ext_vector_type(4))) float f32x4;

// ---- workspace layout (bytes) ----
#define OFF_PERM 256
#define OFF_WB   66816
#define OFF_X    4261120
// total ~38.3 MB

static __device__ __forceinline__ unsigned short f2bf(float f) {
    unsigned int u = __float_as_uint(f);
    u += 0x7fffu + ((u >> 16) & 1u);   // round-to-nearest-even
    return (unsigned short)(u >> 16);
}

// blocks [0,PBLK): role partition via two-sided atomic packing
// (compiler wave-aggregates the +1 atomics: ~2 atomics/wave, not 64)
// blocks [PBLK, PBLK+WBLKS): convert W0|W1 fp32 -> bf16 Wb
__global__ void k_pre(const int* __restrict__ role, int* perm, int* cnt,
                      const float* __restrict__ W0, const float* __restrict__ W1,
                      unsigned short* __restrict__ Wb) {
    int b = blockIdx.x;
    if (b < PBLK) {
        int t = b * 256 + threadIdx.x;           // 0..16383
        int row;
        if (role[t] == 1) { int s = atomicAdd(&cnt[1], 1); row = XROWS - 1 - s; }
        else              { int s = atomicAdd(&cnt[0], 1); row = s; }
        perm[row] = t;
    } else {
        int idx = ((b - PBLK) * 256 + threadIdx.x) * 4;   // 0 .. 2*1048576-4
        const float* src = (idx < 1048576) ? (W0 + idx) : (W1 + (idx - 1048576));
        float4 f = *(const float4*)src;
        *(ushort4*)(Wb + idx) = make_ushort4(f2bf(f.x), f2bf(f.y), f2bf(f.z), f2bf(f.w));
    }
}

// 8 staged rows per block: gather emb[ids[perm[row]]] -> bf16 X[row].
// Row validity decided by cnt bounds (gap rows untouched; GEMM skips them).
// The 8 row-chains are independent -> unrolled loads overlap (MLP).
__global__ void k_gather(const int* __restrict__ ids, const int* __restrict__ perm,
                         const int* __restrict__ cnt, const float* __restrict__ emb,
                         unsigned short* __restrict__ X) {
    int base = blockIdx.x * GROWS;
    int n0 = cnt[0], n1 = cnt[1];
    int t = threadIdx.x;
#pragma unroll
    for (int r = 0; r < GROWS; ++r) {
        int row = base + r;                      // block-uniform
        if (row >= n0 && row < XROWS - n1) continue;   // gap row (scalar branch)
        int p  = perm[row];
        int id = ids[p];
        float4 f = *(const float4*)(emb + (size_t)id * DIM + t * 4);
        *(ushort4*)(X + (size_t)row * DIM + t * 4) =
            make_ushort4(f2bf(f.x), f2bf(f.y), f2bf(f.z), f2bf(f.w));
    }
}

// 128x128 tile GEMM, C = A * B^T: A = X[XROWS,1024] bf16, B^T = W_e rows.
// LDS staged via global_load_lds width=16, XOR swizzle kc^(row&7) on the
// global-gather side so ds_read_b128 fragment reads stay ~conflict-free.
__global__ __launch_bounds__(256, 3)
void k_gemm(const unsigned short* __restrict__ Xu, const unsigned short* __restrict__ Wbu,
            const int* __restrict__ perm, const int* __restrict__ cnt,
            float* __restrict__ out) {
    __shared__ short As[MT * BK];      // 16 KB
    __shared__ short Bs[MT * BK];      // 16 KB

    // XCD swizzle: all 8 n-tiles of an m-tile share one XCD's L2
    int f  = blockIdx.x;
    int mt = ((f >> 6) << 3) | (f & 7);
    int nt = (f >> 3) & 7;
    if (mt >= NTIL) return;

    int n0 = cnt[0], n1 = cnt[1];
    int T0 = (n0 + 127) >> 7, T1 = (n1 + 127) >> 7;
    int e, lo, hi;
    if (mt < T0)              { e = 0; lo = 0;            hi = n0;    }
    else if (mt >= NTIL - T1) { e = 1; lo = XROWS - n1;   hi = XROWS; }
    else return;                           // gap tile

    const short* Ag = (const short*)Xu + (size_t)mt * MT * DIM;
    const short* Bg = (const short*)Wbu + (size_t)e * DIM * DIM + (size_t)nt * MT * DIM;

    int tid  = threadIdx.x;
    int lane = tid & 63;
    int w    = tid >> 6;         // wave 0..3
    int wm   = w & 1, wn = w >> 1;
    int quad = lane >> 4, lq = lane & 15;

    f32x4 acc[4][4] = {};

    for (int k0 = 0; k0 < DIM; k0 += BK) {
#pragma unroll
        for (int i = 0; i < 4; ++i) {
            int q   = w * 4 + i;          // wave-uniform issue id 0..15
            int s   = q * 64 + lane;      // 16B slot index in tile
            int row = s >> 3;
            int kc  = (s & 7) ^ (row & 7);   // swizzled source k-chunk
            __builtin_amdgcn_global_load_lds(
                (const __attribute__((address_space(1))) unsigned int*)(Ag + (size_t)row * DIM + k0 + kc * 8),
                (__attribute__((address_space(3))) unsigned int*)(&As[s * 8]),
                16, 0, 0);
            __builtin_amdgcn_global_load_lds(
                (const __attribute__((address_space(1))) unsigned int*)(Bg + (size_t)row * DIM + k0 + kc * 8),
                (__attribute__((address_space(3))) unsigned int*)(&Bs[s * 8]),
                16, 0, 0);
        }
        __syncthreads();

#pragma unroll
        for (int s = 0; s < 2; ++s) {
            short8 av[4], bv[4];
            int s4q = s * 4 + quad;
#pragma unroll
            for (int i = 0; i < 4; ++i) {
                int ra = wm * 64 + i * 16 + lq;
                av[i] = *(const short8*)&As[(ra * 8 + (s4q ^ (ra & 7))) * 8];
                int rb = wn * 64 + i * 16 + lq;
                bv[i] = *(const short8*)&Bs[(rb * 8 + (s4q ^ (rb & 7))) * 8];
            }
#pragma unroll
            for (int i = 0; i < 4; ++i)
#pragma unroll
                for (int j = 0; j < 4; ++j)
                    acc[i][j] = __builtin_amdgcn_mfma_f32_16x16x32_bf16(
                        av[i], bv[j], acc[i][j], 0, 0, 0);
        }
        __syncthreads();
    }

    // epilogue: C/D map m = quad*4+reg, n = lq; scatter rows to out[token,:]
    int colbase = nt * 128 + wn * 64 + lq;
#pragma unroll
    for (int i = 0; i < 4; ++i) {
#pragma unroll
        for (int r = 0; r < 4; ++r) {
            int mrow = mt * MT + wm * 64 + i * 16 + quad * 4 + r;
            if (mrow < lo || mrow >= hi) continue;   // gap row (bounds, not sentinel)
            int token = perm[mrow];
            float* o = out + (size_t)token * DIM + colbase;
#pragma unroll
            for (int j = 0; j < 4; ++j)
                o[j * 16] = acc[i][j][r];
        }
    }
}

extern "C" void kernel_launch(void* const* d_in, const int* in_sizes, int n_in,
                              void* d_out, int out_size, void* d_ws, size_t ws_size,
                              hipStream_t stream) {
    const int*   ids  = (const int*)d_in[0];
    const int*   role = (const int*)d_in[1];
    const float* emb  = (const float*)d_in[2];
    const float* W0   = (const float*)d_in[3];
    const float* W1   = (const float*)d_in[4];
    float*       out  = (float*)d_out;

    char* ws = (char*)d_ws;
    int* cnt  = (int*)ws;
    int* perm = (int*)(ws + OFF_PERM);
    unsigned short* Wb = (unsigned short*)(ws + OFF_WB);
    unsigned short* X  = (unsigned short*)(ws + OFF_X);

    hipMemsetAsync(cnt, 0x00, 2 * sizeof(int), stream);
    k_pre   <<<PBLK + WBLKS,  256, 0, stream>>>(role, perm, cnt, W0, W1, Wb);
    k_gather<<<XROWS / GROWS, 256, 0, stream>>>(ids, perm, cnt, emb, X);
    k_gemm  <<<1088,          256, 0, stream>>>(X, Wb, perm, cnt, out);
}